// Round 13
// baseline (191.679 us; speedup 1.0000x reference)
//
#include <hip/hip_runtime.h>
#include <hip/hip_bf16.h>
#include <cstdio>

typedef __bf16 bf16x8 __attribute__((ext_vector_type(8)));
typedef float f32x4 __attribute__((ext_vector_type(4)));

#define BM 128
#define BN 128
#define BK 64

__device__ __forceinline__ unsigned short f2bf(float f) {
  union { float f; unsigned u; } v; v.f = f;
  unsigned u = v.u;
  return (unsigned short)((u + 0x7FFFu + ((u >> 16) & 1u)) >> 16);
}

__device__ __forceinline__ float bf2f(unsigned short s) {
  union { unsigned u; float f; } v; v.u = ((unsigned)s) << 16;
  return v.f;
}

#define GLOAD16(gsrc, ldst) \
  __builtin_amdgcn_global_load_lds((const __attribute__((address_space(1))) void*)(gsrc), \
                                   (__attribute__((address_space(3))) void*)(ldst), 16, 0, 0)

// ---------------------------------------------------------------------------
// Shared single-buffered K-loop body (m97-style, verified): ld == 1024, nk=16.
// LDS layout invariant: element (row, k) lives at shorts offset
//   row*64 + ((k>>3) ^ (row&7))*8 + (k&7)      (XOR-swizzled chunks)
// ---------------------------------------------------------------------------
#define SB_KLOOP(Ab, Bb)                                                        \
  for (int kt = 0; kt < 16; kt++) {                                             \
    const unsigned short* Ak = (Ab) + kt * BK;                                  \
    const unsigned short* Bk = (Bb) + kt * BK;                                  \
    _Pragma("unroll")                                                           \
    for (int r = 0; r < 4; r++) {                                               \
      int row = r * 32 + srow;                                                  \
      int sc = sch ^ (row & 7);                                                 \
      GLOAD16(Ak + (long)row * 1024 + sc * 8, &lds[0][(r * 32 + wave * 8) * BK]);\
    }                                                                           \
    _Pragma("unroll")                                                           \
    for (int r = 0; r < 4; r++) {                                               \
      int row = r * 32 + srow;                                                  \
      int sc = sch ^ (row & 7);                                                 \
      GLOAD16(Bk + (long)row * 1024 + sc * 8, &lds[1][(r * 32 + wave * 8) * BK]);\
    }                                                                           \
    __syncthreads();                                                            \
    _Pragma("unroll")                                                           \
    for (int s = 0; s < 2; s++) {                                               \
      bf16x8 av[4], bv[4];                                                      \
      _Pragma("unroll")                                                         \
      for (int i = 0; i < 4; i++) av[i] = *reinterpret_cast<const bf16x8*>(lds[0] + aOff[i][s]); \
      _Pragma("unroll")                                                         \
      for (int j = 0; j < 4; j++) bv[j] = *reinterpret_cast<const bf16x8*>(lds[1] + bOff[j][s]); \
      _Pragma("unroll")                                                         \
      for (int i = 0; i < 4; i++)                                               \
        _Pragma("unroll")                                                       \
        for (int j = 0; j < 4; j++)                                             \
          acc[i][j] = __builtin_amdgcn_mfma_f32_16x16x32_bf16(av[i], bv[j], acc[i][j], 0, 0, 0); \
    }                                                                           \
    __syncthreads();                                                            \
  }

#define SB_PREAMBLE                                                             \
  const int tid = threadIdx.x;                                                  \
  const int lane = tid & 63;                                                    \
  const int wave = tid >> 6;                                                    \
  const int wr = wave >> 1, wc = wave & 1;                                      \
  const int srow = tid >> 3;                                                    \
  const int sch = tid & 7;                                                      \
  (void)srow; (void)sch;                                                        \
  const f32x4 fzero = {0.f, 0.f, 0.f, 0.f};                                     \
  f32x4 acc[4][4];                                                              \
  _Pragma("unroll")                                                             \
  for (int i = 0; i < 4; i++)                                                   \
    _Pragma("unroll")                                                           \
    for (int j = 0; j < 4; j++) acc[i][j] = fzero;                              \
  int aOff[4][2], bOff[4][2];                                                   \
  _Pragma("unroll")                                                             \
  for (int i = 0; i < 4; i++) {                                                 \
    _Pragma("unroll")                                                           \
    for (int s = 0; s < 2; s++) {                                               \
      int ra = wr * 64 + i * 16 + (lane & 15);                                  \
      aOff[i][s] = ra * BK + (((s * 4 + (lane >> 4)) ^ (ra & 7)) * 8);          \
      int rb = wc * 64 + i * 16 + (lane & 15);                                  \
      bOff[i][s] = rb * BK + (((s * 4 + (lane >> 4)) ^ (rb & 7)) * 8);          \
    }                                                                           \
  }

// ---------------------------------------------------------------------------
// cast_wvt: 256 blocks — Wv transpose-cast -> Wvt[m][a] = Wv[a][m] (bf16).
// ---------------------------------------------------------------------------
__global__ __launch_bounds__(256)
void cast_wvt(const float* __restrict__ Wv, unsigned short* __restrict__ Wvt)
{
  __shared__ float t[64][65];
  const int tid = threadIdx.x;
  const int tile = blockIdx.x;                 // 0..255
  const int a0 = (tile >> 4) * 64;
  const int m0 = (tile & 15) * 64;
#pragma unroll
  for (int i = 0; i < 4; i++) {
    const int row = (tid >> 4) + i * 16;
    const int col4 = tid & 15;
    float4 f4 = *reinterpret_cast<const float4*>(Wv + (long)(a0 + row) * 1024 + m0 + col4 * 4);
    t[row][col4 * 4 + 0] = f4.x;
    t[row][col4 * 4 + 1] = f4.y;
    t[row][col4 * 4 + 2] = f4.z;
    t[row][col4 * 4 + 3] = f4.w;
  }
  __syncthreads();
#pragma unroll
  for (int j = 0; j < 2; j++) {
    const int mm = (tid >> 3) + j * 32;
    const int aa0 = (tid & 7) * 8;
    union { unsigned short us[8]; uint4 u4; } pk;
#pragma unroll
    for (int u = 0; u < 8; u++) pk.us[u] = f2bf(t[aa0 + u][mm]);
    *reinterpret_cast<uint4*>(Wvt + (long)(m0 + mm) * 1024 + a0 + aa0) = pk.u4;
  }
}

// ---------------------------------------------------------------------------
// prep2: blocks [0,64)       = Wvo = Wo*Wv GEMM. A staged from fp32 Wo with
//                              inline bf16 cast + swizzled b128 LDS writes
//                              (conflict-free); B = Wvt bf16 via GLOAD16.
//        blocks [64,4160)    = x-cast -> Xbf
//        blocks [4160,5184)  = Wq/Wk casts -> Wqk
// Wvo (64 blocks, L2-resident inputs) hides under the HBM-bound casts.
// ---------------------------------------------------------------------------
__global__ __launch_bounds__(256, 3)
void prep2(const float* __restrict__ x, const float* __restrict__ Wq,
           const float* __restrict__ Wk, const float* __restrict__ Wo,
           const unsigned short* __restrict__ Wvt,
           unsigned short* __restrict__ xb, unsigned short* __restrict__ Wqk,
           unsigned short* __restrict__ Wvo)
{
  __shared__ short lds[2][BM * BK];
  const int blk = blockIdx.x;

  if (blk >= 64) {
    const int tid = threadIdx.x;
    const float* src;
    unsigned short* dst;
    int i;
    if (blk < 4160) {
      src = x; dst = xb; i = ((blk - 64) * 256 + tid) * 8;
    } else {
      const int w = (blk - 4160) >> 9;          // 0,1
      const int off = (blk - 4160) & 511;
      src = (w == 0) ? Wq : Wk;
      dst = Wqk + (long)w * 1024 * 1024;
      i = (off * 256 + tid) * 8;
    }
    float4 a = *reinterpret_cast<const float4*>(src + i);
    float4 b = *reinterpret_cast<const float4*>(src + i + 4);
    union { unsigned short us[8]; uint4 u4; } pk;
    pk.us[0] = f2bf(a.x); pk.us[1] = f2bf(a.y); pk.us[2] = f2bf(a.z); pk.us[3] = f2bf(a.w);
    pk.us[4] = f2bf(b.x); pk.us[5] = f2bf(b.y); pk.us[6] = f2bf(b.z); pk.us[7] = f2bf(b.w);
    *reinterpret_cast<uint4*>(dst + i) = pk.u4;
    return;
  }

  // ---- Wvo GEMM: C[d][m] = sum_a Wo[d][a]*Wv[a][m]
  //      A-row d = Wo row (fp32, inline cast); B-row m = Wvt row (bf16).
  const int m0 = (blk >> 3) * BM, n0 = (blk & 7) * BN;

  SB_PREAMBLE

  for (int kt = 0; kt < 16; kt++) {
    // B via async GLOAD16 (identical to SB_KLOOP B-half)
    const unsigned short* Bk = Wvt + kt * 64;
#pragma unroll
    for (int r = 0; r < 4; r++) {
      int row = r * 32 + srow;
      int sc = sch ^ (row & 7);
      GLOAD16(Bk + (long)(n0 + row) * 1024 + sc * 8, &lds[1][(r * 32 + wave * 8) * BK]);
    }
    // A from Wo fp32: coalesced row reads, inline cast, swizzled b128 writes
#pragma unroll
    for (int p = 0; p < 4; p++) {
      const int row = p * 32 + srow;
      const float* src = Wo + (long)(m0 + row) * 1024 + kt * 64 + sch * 8;
      float4 a4 = *reinterpret_cast<const float4*>(src);
      float4 b4 = *reinterpret_cast<const float4*>(src + 4);
      union { unsigned short us[8]; uint4 u4; } pk;
      pk.us[0] = f2bf(a4.x); pk.us[1] = f2bf(a4.y); pk.us[2] = f2bf(a4.z); pk.us[3] = f2bf(a4.w);
      pk.us[4] = f2bf(b4.x); pk.us[5] = f2bf(b4.y); pk.us[6] = f2bf(b4.z); pk.us[7] = f2bf(b4.w);
      *reinterpret_cast<uint4*>(&lds[0][row * 64 + ((sch ^ (row & 7)) * 8)]) = pk.u4;
    }
    __syncthreads();   // drains vmcnt (B) + lgkmcnt (A writes)
#pragma unroll
    for (int s = 0; s < 2; s++) {
      bf16x8 av[4], bv[4];
#pragma unroll
      for (int i = 0; i < 4; i++) av[i] = *reinterpret_cast<const bf16x8*>(lds[0] + aOff[i][s]);
#pragma unroll
      for (int j = 0; j < 4; j++) bv[j] = *reinterpret_cast<const bf16x8*>(lds[1] + bOff[j][s]);
#pragma unroll
      for (int i = 0; i < 4; i++)
#pragma unroll
        for (int j = 0; j < 4; j++)
          acc[i][j] = __builtin_amdgcn_mfma_f32_16x16x32_bf16(av[i], bv[j], acc[i][j], 0, 0, 0);
    }
    __syncthreads();
  }

  const int rb4 = (lane >> 4) * 4;
  const int cl = lane & 15;
#pragma unroll
  for (int i = 0; i < 4; i++) {
#pragma unroll
    for (int j = 0; j < 4; j++) {
      const int gm = m0 + wr * 64 + i * 16 + rb4;
      const int gn = n0 + wc * 64 + j * 16 + cl;
#pragma unroll
      for (int r = 0; r < 4; r++)
        Wvo[(long)(gm + r) * 1024 + gn] = f2bf(acc[i][j][r]);
    }
  }
}

// ---------------------------------------------------------------------------
// dispA2: blocks [0,1024) = QK projection (M=8192, N=2048);
//         blocks [1024,1536) = VW = X*Wvo^T (transposed store -> VWt).
// 1536 blocks = exactly 2 rounds @3/CU.
// ---------------------------------------------------------------------------
__global__ __launch_bounds__(256, 3)
void dispA2(const unsigned short* __restrict__ Xbf, const unsigned short* __restrict__ Wqk,
            const unsigned short* __restrict__ Wvo,
            unsigned short* __restrict__ Qb, unsigned short* __restrict__ Kb,
            unsigned short* __restrict__ VWt)
{
  __shared__ short lds[2][BM * BK];
  const int flat = blockIdx.x;
  const bool isQK = flat < 1024;
  int m0, n0;
  const unsigned short *Ab, *Bb;
  if (isQK) {
    const int swz = (flat & 7) * 128 + (flat >> 3);   // m204, nwg=1024 (r=0)
    const int bx = swz & 15, by = swz >> 4;           // gx=16
    m0 = by * BM; n0 = bx * BN;
    Ab = Xbf + (long)m0 * 1024;
    Bb = Wqk + (long)n0 * 1024;
  } else {
    const int t = flat - 1024;                        // 0..511
    const int swz = (t & 7) * 64 + (t >> 3);          // m204, nwg=512 (r=0)
    const int bx = swz & 7, by = swz >> 3;            // gx=8
    m0 = by * BM; n0 = bx * BN;
    Ab = Xbf + (long)m0 * 1024;
    Bb = Wvo + (long)n0 * 1024;
  }

  SB_PREAMBLE
  SB_KLOOP(Ab, Bb)

  const int rb4 = (lane >> 4) * 4;
  const int cl = lane & 15;
#pragma unroll
  for (int i = 0; i < 4; i++) {
#pragma unroll
    for (int j = 0; j < 4; j++) {
      const int gm = m0 + wr * 64 + i * 16 + rb4;
      const int gn = n0 + wc * 64 + j * 16 + cl;
      if (isQK) {
        if (gn < 1024) {
#pragma unroll
          for (int r = 0; r < 4; r++)
            Qb[(long)(gm + r) * 1024 + gn] = f2bf(acc[i][j][r]);
        } else {
#pragma unroll
          for (int r = 0; r < 4; r++)
            Kb[(long)(gm + r) * 1024 + (gn - 1024)] = f2bf(acc[i][j][r]);
        }
      } else {
        // transposed store: VWt[b][d=gn][s], b = gm>>11, s = gm&2047
        const int b = gm >> 11;
        const int sIdx = gm & 2047;
        unsigned short* C = VWt + (long)b * (2048L * 1024) + (long)gn * 2048 + sIdx;
        ushort4 pk;
        pk.x = f2bf(acc[i][j][0]);
        pk.y = f2bf(acc[i][j][1]);
        pk.z = f2bf(acc[i][j][2]);
        pk.w = f2bf(acc[i][j][3]);
        *reinterpret_cast<ushort4*>(C) = pk;
      }
    }
  }
}

// ---------------------------------------------------------------------------
// dispS: S = Q K^T / 32, packed lower-triangular (136 tiles x 4 batches).
// ---------------------------------------------------------------------------
__global__ __launch_bounds__(256, 3)
void dispS(const unsigned short* __restrict__ Qb, const unsigned short* __restrict__ Kb,
           unsigned short* __restrict__ Sb)
{
  __shared__ short lds[2][BM * BK];
  const int t = blockIdx.x;                           // 0..543
  const int bz = t / 136;
  const int tt = t - bz * 136;
  const int swz = (tt & 7) * 17 + (tt >> 3);          // m204, nwg=136 (17x8, r=0)
  int i = (int)((sqrtf(8.f * (float)swz + 1.f) - 1.f) * 0.5f);
  while ((i + 1) * (i + 2) / 2 <= swz) ++i;
  while (i * (i + 1) / 2 > swz) --i;
  const int j = swz - i * (i + 1) / 2;
  const int m0 = i * BM, n0 = j * BN;
  const unsigned short* Ab = Qb + ((long)bz * 2048 + m0) * 1024;
  const unsigned short* Bb = Kb + ((long)bz * 2048 + n0) * 1024;

  SB_PREAMBLE
  SB_KLOOP(Ab, Bb)

  const int rb4 = (lane >> 4) * 4;
  const int cl = lane & 15;
  unsigned short* C = Sb + (long)bz * (2048L * 2048);
#pragma unroll
  for (int ii = 0; ii < 4; ii++) {
#pragma unroll
    for (int jj = 0; jj < 4; jj++) {
      const int gm = m0 + wr * 64 + ii * 16 + rb4;
      const int gn = n0 + wc * 64 + jj * 16 + cl;
#pragma unroll
      for (int r = 0; r < 4; r++)
        C[(long)(gm + r) * 2048 + gn] = f2bf(acc[ii][jj][r] * 0.03125f);
    }
  }
}

// ---------------------------------------------------------------------------
// Double-buffered counted-vmcnt 128x128 GEMM-BT: PV -> out fp32+bias.
// Balanced causal pairing (z>=2 flips m).
// ---------------------------------------------------------------------------
__global__ __launch_bounds__(256, 2)
void gemm_pv(const unsigned short* __restrict__ A, const unsigned short* __restrict__ B,
             float* __restrict__ Cv, const float* __restrict__ bias,
             int K, int ldA, int ldB, int ldC,
             long aBat, long bBat, long cBat)
{
  const int gx = gridDim.x;
  const int nwg = gx * gridDim.y;
  const int flat = blockIdx.y * gx + blockIdx.x;
  const int qch = nwg >> 3, rch = nwg & 7;
  const int xcd = flat & 7, idx = flat >> 3;
  const int swz = (xcd < rch ? xcd * (qch + 1) : rch * (qch + 1) + (xcd - rch) * qch) + idx;
  const int bx = swz % gx;
  const int bz = blockIdx.z;
  int by = swz / gx;
  if (bz >= 2) by = gridDim.y - 1 - by;      // complementary-Keff pairing

  const int m0 = by * BM;
  const int n0 = bx * BN;

  const unsigned short* Ab = A + (long)bz * aBat + (long)m0 * ldA;
  const unsigned short* Bb = B + (long)bz * bBat + (long)n0 * ldB;

  __shared__ short lds[2][2][BM * BK];

  const int tid = threadIdx.x;
  const int lane = tid & 63;
  const int wave = tid >> 6;
  const int wr = wave >> 1, wc = wave & 1;

  const int Keff = min(K, m0 + BM);          // causal K-limit
  const int nk = Keff / BK;

  const int srow = tid >> 3;
  const int sch = tid & 7;

  const f32x4 fzero = {0.f, 0.f, 0.f, 0.f};
  f32x4 acc[4][4];
#pragma unroll
  for (int i = 0; i < 4; i++)
#pragma unroll
    for (int j = 0; j < 4; j++) acc[i][j] = fzero;

  int aOff[4][2], bOff[4][2];
#pragma unroll
  for (int i = 0; i < 4; i++) {
#pragma unroll
    for (int s = 0; s < 2; s++) {
      int ra = wr * 64 + i * 16 + (lane & 15);
      aOff[i][s] = ra * BK + (((s * 4 + (lane >> 4)) ^ (ra & 7)) * 8);
      int rb = wc * 64 + i * 16 + (lane & 15);
      bOff[i][s] = rb * BK + (((s * 4 + (lane >> 4)) ^ (rb & 7)) * 8);
    }
  }

  auto stage = [&](int buf, int kt) {
    const unsigned short* Ak = Ab + kt * BK;
    const unsigned short* Bk = Bb + kt * BK;
#pragma unroll
    for (int r = 0; r < 4; r++) {
      int row = r * 32 + srow;
      int sc = sch ^ (row & 7);
      GLOAD16(Ak + (long)row * ldA + sc * 8, &lds[buf][0][(r * 32 + wave * 8) * BK]);
    }
#pragma unroll
    for (int r = 0; r < 4; r++) {
      int row = r * 32 + srow;
      int sc = sch ^ (row & 7);
      GLOAD16(Bk + (long)row * ldB + sc * 8, &lds[buf][1][(r * 32 + wave * 8) * BK]);
    }
  };

  stage(0, 0);
  stage(1, 1);
  asm volatile("s_waitcnt vmcnt(8)" ::: "memory");
  __builtin_amdgcn_sched_barrier(0);
  __builtin_amdgcn_s_barrier();

  int cur = 0;
  for (int kt = 0; kt < nk; kt++) {
    const short* La = lds[cur][0];
    const short* Lb = lds[cur][1];
    bf16x8 av[2][4], bv[2][4];
#pragma unroll
    for (int s = 0; s < 2; s++) {
#pragma unroll
      for (int i = 0; i < 4; i++) {
        av[s][i] = *reinterpret_cast<const bf16x8*>(La + aOff[i][s]);
        bv[s][i] = *reinterpret_cast<const bf16x8*>(Lb + bOff[i][s]);
      }
    }
    asm volatile("s_waitcnt lgkmcnt(0)" ::: "memory");
    __builtin_amdgcn_sched_barrier(0);
    __builtin_amdgcn_s_barrier();
    __builtin_amdgcn_sched_barrier(0);

    if (kt + 2 < nk) {
      stage(cur, kt + 2);
      asm volatile("s_waitcnt vmcnt(8)" ::: "memory");
    } else if (kt + 1 < nk) {
      asm volatile("s_waitcnt vmcnt(0)" ::: "memory");
    }
    if (kt + 1 < nk) {
      __builtin_amdgcn_s_barrier();
      __builtin_amdgcn_sched_barrier(0);
    }

    __builtin_amdgcn_s_setprio(1);
#pragma unroll
    for (int s = 0; s < 2; s++)
#pragma unroll
      for (int i = 0; i < 4; i++)
#pragma unroll
        for (int j = 0; j < 4; j++)
          acc[i][j] = __builtin_amdgcn_mfma_f32_16x16x32_bf16(av[s][i], bv[s][j], acc[i][j], 0, 0, 0);
    __builtin_amdgcn_s_setprio(0);
    __builtin_amdgcn_sched_barrier(0);
    cur ^= 1;
  }

  const int rb4 = (lane >> 4) * 4;
  const int cl = lane & 15;
#pragma unroll
  for (int i = 0; i < 4; i++) {
#pragma unroll
    for (int j = 0; j < 4; j++) {
      const int gm = m0 + wr * 64 + i * 16 + rb4;
      const int gn = n0 + wc * 64 + j * 16 + cl;
      float* C = Cv + (long)bz * cBat;
      const float bb = bias[gn];
#pragma unroll
      for (int r = 0; r < 4; r++)
        C[(long)(gm + r) * ldC + gn] = acc[i][j][r] + bb;
    }
  }
}

// one WAVE per (q row); 4 rows per block; shfl-only reduction.
__global__ __launch_bounds__(256)
void softmax_rows(const unsigned short* __restrict__ Sb, const float* __restrict__ maskv,
                  unsigned short* __restrict__ P, int Sdim)
{
  const int wv = threadIdx.x >> 6;
  const int lane = threadIdx.x & 63;
  const int q = blockIdx.x * 4 + wv;
  const int b = blockIdx.y;
  const int kmax = (q & ~127) + 128;
  const unsigned short* row = Sb + ((long)b * Sdim + q) * Sdim;
  unsigned short* prow = P + ((long)b * Sdim + q) * Sdim;
  const float* mrow = maskv + (long)b * Sdim;
  const float mq = mrow[q];

  float v[4][8];
  float mx = -INFINITY;
#pragma unroll
  for (int c = 0; c < 4; c++) {
    const int k0 = c * 512 + lane * 8;
    if (c * 512 < kmax) {
      uint4 raw = *reinterpret_cast<const uint4*>(row + k0);
      const unsigned short* us = reinterpret_cast<const unsigned short*>(&raw);
      float4 ma = *reinterpret_cast<const float4*>(mrow + k0);
      float4 mb = *reinterpret_cast<const float4*>(mrow + k0 + 4);
      float mv[8] = {ma.x, ma.y, ma.z, ma.w, mb.x, mb.y, mb.z, mb.w};
#pragma unroll
      for (int u = 0; u < 8; u++) {
        const int k = k0 + u;
        const bool ok = (k <= q) && (mq * mv[u] == 1.0f);   // square_mask == 1 semantics
        v[c][u] = ok ? bf2f(us[u]) : -INFINITY;
        mx = fmaxf(mx, v[c][u]);
      }
    } else {
#pragma unroll
      for (int u = 0; u < 8; u++) v[c][u] = -INFINITY;
    }
  }
#pragma unroll
  for (int o = 32; o; o >>= 1) mx = fmaxf(mx, __shfl_xor(mx, o));

  float sm = 0.f;
#pragma unroll
  for (int c = 0; c < 4; c++)
#pragma unroll
    for (int u = 0; u < 8; u++) {
      v[c][u] = (v[c][u] > -INFINITY) ? __expf(v[c][u] - mx) : 0.f;
      sm += v[c][u];
    }
#pragma unroll
  for (int o = 32; o; o >>= 1) sm += __shfl_xor(sm, o);
  const float inv = 1.0f / sm;

#pragma unroll
  for (int c = 0; c < 4; c++) {
    if (c * 512 < kmax) {
      union { unsigned short us[8]; uint4 u4; } pk;
#pragma unroll
      for (int u = 0; u < 8; u++) pk.us[u] = f2bf(v[c][u] * inv);
      *reinterpret_cast<uint4*>(prow + c * 512 + lane * 8) = pk.u4;
    }
  }
}

extern "C" void kernel_launch(void* const* d_in, const int* in_sizes, int n_in,
                              void* d_out, int out_size, void* d_ws, size_t ws_size,
                              hipStream_t stream)
{
  const int B = 4, S = 2048, D = 1024;
  const float* x  = (const float*)d_in[0];
  const float* mk = (const float*)d_in[1];
  const float* Wq = (const float*)d_in[2];
  const float* Wk = (const float*)d_in[3];
  const float* Wv = (const float*)d_in[4];
  const float* Wo = (const float*)d_in[5];
  const float* bo = (const float*)d_in[6];
  float* out = (float*)d_out;

  char* ws = (char*)d_ws;
  const long MB = 1024L * 1024L;
  unsigned short* Xbf  = (unsigned short*)(ws + 0);        // 16MB (live through dispA2)
  unsigned short* Qb   = (unsigned short*)(ws + 16 * MB);  // 16MB [8192][1024]; -> P
  unsigned short* Kb   = (unsigned short*)(ws + 32 * MB);  // 16MB [8192][1024]; -> P
  unsigned short* VWt  = (unsigned short*)(ws + 48 * MB);  // 16MB VW^T per batch [D][S]
  unsigned short* Wqk  = (unsigned short*)(ws + 64 * MB);  // 4MB [2048][1024] Wq|Wk
  unsigned short* Wvo  = (unsigned short*)(ws + 68 * MB);  // 2MB [1024][1024]
  unsigned short* Sbuf = (unsigned short*)(ws + 72 * MB);  // 32MB bf16 logits
  unsigned short* Wvt  = Sbuf;                             // 2MB overlay (dead before dispS)
  unsigned short* P    = Qb;                               // 32MB over dead Q+K

  if (ws_size < (size_t)(104 * MB)) {
    fprintf(stderr, "kernel_launch: ws too small (%zu bytes, need 104MB)\n", ws_size);
    return;
  }

  // 1) Wv transpose-cast only (256 blocks)
  cast_wvt<<<dim3(256), dim3(256), 0, stream>>>(Wv, Wvt);
  // 2) Wvo GEMM (fp32-A staged, 64 blocks) hidden under x/Wq/Wk casts
  prep2<<<dim3(5184), dim3(256), 0, stream>>>(x, Wq, Wk, Wo, Wvt, Xbf, Wqk, Wvo);
  // 3) QK projection (1024) || VW = X*Wvo^T (512) — 2 clean rounds @3/CU
  dispA2<<<dim3(1536), dim3(256), 0, stream>>>(Xbf, Wqk, Wvo, Qb, Kb, VWt);
  // 4) S = Q K^T / 32, packed triangular (544 blocks, one round)
  dispS<<<dim3(544), dim3(256), 0, stream>>>(Qb, Kb, Sbuf);
  // 5) softmax -> P bf16
  softmax_rows<<<dim3(512, 4), dim3(256), 0, stream>>>(Sbuf, mk, P, 2048);
  // 6) out = P * VWt^T + bo (fp32 direct, causal K-limit, balanced pairing)
  dim3 gO(1024 / BN, 2048 / BM, 4);
  gemm_pv<<<gO, dim3(256), 0, stream>>>(P, VWt, out, bo,
                                        2048, 2048, 2048, 1024,
                                        (long)S * S, (long)D * S, (long)S * D);
}

// Round 14
// 155.889 us; speedup vs baseline: 1.2296x; 1.2296x over previous
//
#include <hip/hip_runtime.h>
#include <hip/hip_bf16.h>
#include <cstdio>

typedef __bf16 bf16x8 __attribute__((ext_vector_type(8)));
typedef float f32x4 __attribute__((ext_vector_type(4)));

#define BM 128
#define BN 128
#define BK 64

__device__ __forceinline__ unsigned short f2bf(float f) {
  union { float f; unsigned u; } v; v.f = f;
  unsigned u = v.u;
  return (unsigned short)((u + 0x7FFFu + ((u >> 16) & 1u)) >> 16);
}

__device__ __forceinline__ float bf2f(unsigned short s) {
  union { unsigned u; float f; } v; v.u = ((unsigned)s) << 16;
  return v.f;
}

#define GLOAD16(gsrc, ldst) \
  __builtin_amdgcn_global_load_lds((const __attribute__((address_space(1))) void*)(gsrc), \
                                   (__attribute__((address_space(3))) void*)(ldst), 16, 0, 0)

// ---------------------------------------------------------------------------
// Shared single-buffered K-loop body (m97-style, verified): ld == 1024, nk=16.
// LDS layout invariant: element (row, k) lives at shorts offset
//   row*64 + ((k>>3) ^ (row&7))*8 + (k&7)      (XOR-swizzled chunks)
// ---------------------------------------------------------------------------
#define SB_KLOOP(Ab, Bb)                                                        \
  for (int kt = 0; kt < 16; kt++) {                                             \
    const unsigned short* Ak = (Ab) + kt * BK;                                  \
    const unsigned short* Bk = (Bb) + kt * BK;                                  \
    _Pragma("unroll")                                                           \
    for (int r = 0; r < 4; r++) {                                               \
      int row = r * 32 + srow;                                                  \
      int sc = sch ^ (row & 7);                                                 \
      GLOAD16(Ak + (long)row * 1024 + sc * 8, &lds[0][(r * 32 + wave * 8) * BK]);\
    }                                                                           \
    _Pragma("unroll")                                                           \
    for (int r = 0; r < 4; r++) {                                               \
      int row = r * 32 + srow;                                                  \
      int sc = sch ^ (row & 7);                                                 \
      GLOAD16(Bk + (long)row * 1024 + sc * 8, &lds[1][(r * 32 + wave * 8) * BK]);\
    }                                                                           \
    __syncthreads();                                                            \
    _Pragma("unroll")                                                           \
    for (int s = 0; s < 2; s++) {                                               \
      bf16x8 av[4], bv[4];                                                      \
      _Pragma("unroll")                                                         \
      for (int i = 0; i < 4; i++) av[i] = *reinterpret_cast<const bf16x8*>(lds[0] + aOff[i][s]); \
      _Pragma("unroll")                                                         \
      for (int j = 0; j < 4; j++) bv[j] = *reinterpret_cast<const bf16x8*>(lds[1] + bOff[j][s]); \
      _Pragma("unroll")                                                         \
      for (int i = 0; i < 4; i++)                                               \
        _Pragma("unroll")                                                       \
        for (int j = 0; j < 4; j++)                                             \
          acc[i][j] = __builtin_amdgcn_mfma_f32_16x16x32_bf16(av[i], bv[j], acc[i][j], 0, 0, 0); \
    }                                                                           \
    __syncthreads();                                                            \
  }

#define SB_PREAMBLE                                                             \
  const int tid = threadIdx.x;                                                  \
  const int lane = tid & 63;                                                    \
  const int wave = tid >> 6;                                                    \
  const int wr = wave >> 1, wc = wave & 1;                                      \
  const int srow = tid >> 3;                                                    \
  const int sch = tid & 7;                                                      \
  (void)srow; (void)sch;                                                        \
  const f32x4 fzero = {0.f, 0.f, 0.f, 0.f};                                     \
  f32x4 acc[4][4];                                                              \
  _Pragma("unroll")                                                             \
  for (int i = 0; i < 4; i++)                                                   \
    _Pragma("unroll")                                                           \
    for (int j = 0; j < 4; j++) acc[i][j] = fzero;                              \
  int aOff[4][2], bOff[4][2];                                                   \
  _Pragma("unroll")                                                             \
  for (int i = 0; i < 4; i++) {                                                 \
    _Pragma("unroll")                                                           \
    for (int s = 0; s < 2; s++) {                                               \
      int ra = wr * 64 + i * 16 + (lane & 15);                                  \
      aOff[i][s] = ra * BK + (((s * 4 + (lane >> 4)) ^ (ra & 7)) * 8);          \
      int rb = wc * 64 + i * 16 + (lane & 15);                                  \
      bOff[i][s] = rb * BK + (((s * 4 + (lane >> 4)) ^ (rb & 7)) * 8);          \
    }                                                                           \
  }

// ---------------------------------------------------------------------------
// cast_ow: blocks [0,512) Wo cast -> Wob (bf16);
//          blocks [512,768) Wv transpose-cast -> Wvt[m][a] = Wv[a][m].
// Only what the Wvo GEMM consumes — Wq/Wk casts moved into prep2.
// ---------------------------------------------------------------------------
__global__ __launch_bounds__(256)
void cast_ow(const float* __restrict__ Wo, const float* __restrict__ Wv,
             unsigned short* __restrict__ Wob, unsigned short* __restrict__ Wvt)
{
  __shared__ float t[64][65];
  const int blk = blockIdx.x;
  const int tid = threadIdx.x;
  if (blk < 512) {
    const int i = (blk * 256 + tid) * 8;
    float4 a = *reinterpret_cast<const float4*>(Wo + i);
    float4 b = *reinterpret_cast<const float4*>(Wo + i + 4);
    union { unsigned short us[8]; uint4 u4; } pk;
    pk.us[0] = f2bf(a.x); pk.us[1] = f2bf(a.y); pk.us[2] = f2bf(a.z); pk.us[3] = f2bf(a.w);
    pk.us[4] = f2bf(b.x); pk.us[5] = f2bf(b.y); pk.us[6] = f2bf(b.z); pk.us[7] = f2bf(b.w);
    *reinterpret_cast<uint4*>(Wob + i) = pk.u4;
    return;
  }
  // Wv transpose-cast: 64x64 tile per block
  const int tile = blk - 512;                  // 0..255
  const int a0 = (tile >> 4) * 64;
  const int m0 = (tile & 15) * 64;
#pragma unroll
  for (int i = 0; i < 4; i++) {
    const int row = (tid >> 4) + i * 16;
    const int col4 = tid & 15;
    float4 f4 = *reinterpret_cast<const float4*>(Wv + (long)(a0 + row) * 1024 + m0 + col4 * 4);
    t[row][col4 * 4 + 0] = f4.x;
    t[row][col4 * 4 + 1] = f4.y;
    t[row][col4 * 4 + 2] = f4.z;
    t[row][col4 * 4 + 3] = f4.w;
  }
  __syncthreads();
#pragma unroll
  for (int j = 0; j < 2; j++) {
    const int mm = (tid >> 3) + j * 32;
    const int aa0 = (tid & 7) * 8;
    union { unsigned short us[8]; uint4 u4; } pk;
#pragma unroll
    for (int u = 0; u < 8; u++) pk.us[u] = f2bf(t[aa0 + u][mm]);
    *reinterpret_cast<uint4*>(Wvt + (long)(m0 + mm) * 1024 + a0 + aa0) = pk.u4;
  }
}

// ---------------------------------------------------------------------------
// prep2: blocks [0,64)       = Wvo = Wo*Wv GEMM (bf16 inputs Wob/Wvt via
//                              GLOAD16 — the R10-proven fast path);
//        blocks [64,4160)    = x-cast -> Xbf;
//        blocks [4160,5184)  = Wq/Wk casts -> Wqk.
// Wvo (64 blocks, L2-resident 4MB bf16 inputs) hides under the HBM casts.
// ---------------------------------------------------------------------------
__global__ __launch_bounds__(256, 3)
void prep2(const float* __restrict__ x, const float* __restrict__ Wq,
           const float* __restrict__ Wk,
           const unsigned short* __restrict__ Wob, const unsigned short* __restrict__ Wvt,
           unsigned short* __restrict__ xb, unsigned short* __restrict__ Wqk,
           unsigned short* __restrict__ Wvo)
{
  __shared__ short lds[2][BM * BK];
  const int blk = blockIdx.x;

  if (blk >= 64) {
    const int tid = threadIdx.x;
    const float* src;
    unsigned short* dst;
    int i;
    if (blk < 4160) {
      src = x; dst = xb; i = ((blk - 64) * 256 + tid) * 8;
    } else {
      const int w = (blk - 4160) >> 9;          // 0,1
      const int off = (blk - 4160) & 511;
      src = (w == 0) ? Wq : Wk;
      dst = Wqk + (long)w * 1024 * 1024;
      i = (off * 256 + tid) * 8;
    }
    float4 a = *reinterpret_cast<const float4*>(src + i);
    float4 b = *reinterpret_cast<const float4*>(src + i + 4);
    union { unsigned short us[8]; uint4 u4; } pk;
    pk.us[0] = f2bf(a.x); pk.us[1] = f2bf(a.y); pk.us[2] = f2bf(a.z); pk.us[3] = f2bf(a.w);
    pk.us[4] = f2bf(b.x); pk.us[5] = f2bf(b.y); pk.us[6] = f2bf(b.z); pk.us[7] = f2bf(b.w);
    *reinterpret_cast<uint4*>(dst + i) = pk.u4;
    return;
  }

  // ---- Wvo GEMM: C[d][m] = sum_a Wo[d][a]*Wv[a][m] — bf16 GLOAD16 both sides
  const int t = blk;                           // 0..63, 8x8 grid
  const int m0 = (t >> 3) * BM, n0 = (t & 7) * BN;
  const unsigned short* Ab = Wob + (long)m0 * 1024;
  const unsigned short* Bb = Wvt + (long)n0 * 1024;

  SB_PREAMBLE
  SB_KLOOP(Ab, Bb)

  const int rb4 = (lane >> 4) * 4;
  const int cl = lane & 15;
#pragma unroll
  for (int i = 0; i < 4; i++) {
#pragma unroll
    for (int j = 0; j < 4; j++) {
      const int gm = m0 + wr * 64 + i * 16 + rb4;
      const int gn = n0 + wc * 64 + j * 16 + cl;
#pragma unroll
      for (int r = 0; r < 4; r++)
        Wvo[(long)(gm + r) * 1024 + gn] = f2bf(acc[i][j][r]);
    }
  }
}

// ---------------------------------------------------------------------------
// dispA2: blocks [0,1024) = QK projection (M=8192, N=2048);
//         blocks [1024,1536) = VW = X*Wvo^T (transposed store -> VWt).
// 1536 blocks = exactly 2 rounds @3/CU.
// ---------------------------------------------------------------------------
__global__ __launch_bounds__(256, 3)
void dispA2(const unsigned short* __restrict__ Xbf, const unsigned short* __restrict__ Wqk,
            const unsigned short* __restrict__ Wvo,
            unsigned short* __restrict__ Qb, unsigned short* __restrict__ Kb,
            unsigned short* __restrict__ VWt)
{
  __shared__ short lds[2][BM * BK];
  const int flat = blockIdx.x;
  const bool isQK = flat < 1024;
  int m0, n0;
  const unsigned short *Ab, *Bb;
  if (isQK) {
    const int swz = (flat & 7) * 128 + (flat >> 3);   // m204, nwg=1024 (r=0)
    const int bx = swz & 15, by = swz >> 4;           // gx=16
    m0 = by * BM; n0 = bx * BN;
    Ab = Xbf + (long)m0 * 1024;
    Bb = Wqk + (long)n0 * 1024;
  } else {
    const int t = flat - 1024;                        // 0..511
    const int swz = (t & 7) * 64 + (t >> 3);          // m204, nwg=512 (r=0)
    const int bx = swz & 7, by = swz >> 3;            // gx=8
    m0 = by * BM; n0 = bx * BN;
    Ab = Xbf + (long)m0 * 1024;
    Bb = Wvo + (long)n0 * 1024;
  }

  SB_PREAMBLE
  SB_KLOOP(Ab, Bb)

  const int rb4 = (lane >> 4) * 4;
  const int cl = lane & 15;
#pragma unroll
  for (int i = 0; i < 4; i++) {
#pragma unroll
    for (int j = 0; j < 4; j++) {
      const int gm = m0 + wr * 64 + i * 16 + rb4;
      const int gn = n0 + wc * 64 + j * 16 + cl;
      if (isQK) {
        if (gn < 1024) {
#pragma unroll
          for (int r = 0; r < 4; r++)
            Qb[(long)(gm + r) * 1024 + gn] = f2bf(acc[i][j][r]);
        } else {
#pragma unroll
          for (int r = 0; r < 4; r++)
            Kb[(long)(gm + r) * 1024 + (gn - 1024)] = f2bf(acc[i][j][r]);
        }
      } else {
        // transposed store: VWt[b][d=gn][s], b = gm>>11, s = gm&2047
        const int b = gm >> 11;
        const int sIdx = gm & 2047;
        unsigned short* C = VWt + (long)b * (2048L * 1024) + (long)gn * 2048 + sIdx;
        ushort4 pk;
        pk.x = f2bf(acc[i][j][0]);
        pk.y = f2bf(acc[i][j][1]);
        pk.z = f2bf(acc[i][j][2]);
        pk.w = f2bf(acc[i][j][3]);
        *reinterpret_cast<ushort4*>(C) = pk;
      }
    }
  }
}

// ---------------------------------------------------------------------------
// dispS: S = Q K^T / 32, packed lower-triangular (136 tiles x 4 batches).
// ---------------------------------------------------------------------------
__global__ __launch_bounds__(256, 3)
void dispS(const unsigned short* __restrict__ Qb, const unsigned short* __restrict__ Kb,
           unsigned short* __restrict__ Sb)
{
  __shared__ short lds[2][BM * BK];
  const int t = blockIdx.x;                           // 0..543
  const int bz = t / 136;
  const int tt = t - bz * 136;
  const int swz = (tt & 7) * 17 + (tt >> 3);          // m204, nwg=136 (17x8, r=0)
  int i = (int)((sqrtf(8.f * (float)swz + 1.f) - 1.f) * 0.5f);
  while ((i + 1) * (i + 2) / 2 <= swz) ++i;
  while (i * (i + 1) / 2 > swz) --i;
  const int j = swz - i * (i + 1) / 2;
  const int m0 = i * BM, n0 = j * BN;
  const unsigned short* Ab = Qb + ((long)bz * 2048 + m0) * 1024;
  const unsigned short* Bb = Kb + ((long)bz * 2048 + n0) * 1024;

  SB_PREAMBLE
  SB_KLOOP(Ab, Bb)

  const int rb4 = (lane >> 4) * 4;
  const int cl = lane & 15;
  unsigned short* C = Sb + (long)bz * (2048L * 2048);
#pragma unroll
  for (int ii = 0; ii < 4; ii++) {
#pragma unroll
    for (int jj = 0; jj < 4; jj++) {
      const int gm = m0 + wr * 64 + ii * 16 + rb4;
      const int gn = n0 + wc * 64 + jj * 16 + cl;
#pragma unroll
      for (int r = 0; r < 4; r++)
        C[(long)(gm + r) * 2048 + gn] = f2bf(acc[ii][jj][r] * 0.03125f);
    }
  }
}

// ---------------------------------------------------------------------------
// Double-buffered counted-vmcnt 128x128 GEMM-BT: PV -> out fp32+bias.
// Balanced causal pairing (z>=2 flips m).
// ---------------------------------------------------------------------------
__global__ __launch_bounds__(256, 2)
void gemm_pv(const unsigned short* __restrict__ A, const unsigned short* __restrict__ B,
             float* __restrict__ Cv, const float* __restrict__ bias,
             int K, int ldA, int ldB, int ldC,
             long aBat, long bBat, long cBat)
{
  const int gx = gridDim.x;
  const int nwg = gx * gridDim.y;
  const int flat = blockIdx.y * gx + blockIdx.x;
  const int qch = nwg >> 3, rch = nwg & 7;
  const int xcd = flat & 7, idx = flat >> 3;
  const int swz = (xcd < rch ? xcd * (qch + 1) : rch * (qch + 1) + (xcd - rch) * qch) + idx;
  const int bx = swz % gx;
  const int bz = blockIdx.z;
  int by = swz / gx;
  if (bz >= 2) by = gridDim.y - 1 - by;      // complementary-Keff pairing

  const int m0 = by * BM;
  const int n0 = bx * BN;

  const unsigned short* Ab = A + (long)bz * aBat + (long)m0 * ldA;
  const unsigned short* Bb = B + (long)bz * bBat + (long)n0 * ldB;

  __shared__ short lds[2][2][BM * BK];

  const int tid = threadIdx.x;
  const int lane = tid & 63;
  const int wave = tid >> 6;
  const int wr = wave >> 1, wc = wave & 1;

  const int Keff = min(K, m0 + BM);          // causal K-limit
  const int nk = Keff / BK;

  const int srow = tid >> 3;
  const int sch = tid & 7;

  const f32x4 fzero = {0.f, 0.f, 0.f, 0.f};
  f32x4 acc[4][4];
#pragma unroll
  for (int i = 0; i < 4; i++)
#pragma unroll
    for (int j = 0; j < 4; j++) acc[i][j] = fzero;

  int aOff[4][2], bOff[4][2];
#pragma unroll
  for (int i = 0; i < 4; i++) {
#pragma unroll
    for (int s = 0; s < 2; s++) {
      int ra = wr * 64 + i * 16 + (lane & 15);
      aOff[i][s] = ra * BK + (((s * 4 + (lane >> 4)) ^ (ra & 7)) * 8);
      int rb = wc * 64 + i * 16 + (lane & 15);
      bOff[i][s] = rb * BK + (((s * 4 + (lane >> 4)) ^ (rb & 7)) * 8);
    }
  }

  auto stage = [&](int buf, int kt) {
    const unsigned short* Ak = Ab + kt * BK;
    const unsigned short* Bk = Bb + kt * BK;
#pragma unroll
    for (int r = 0; r < 4; r++) {
      int row = r * 32 + srow;
      int sc = sch ^ (row & 7);
      GLOAD16(Ak + (long)row * ldA + sc * 8, &lds[buf][0][(r * 32 + wave * 8) * BK]);
    }
#pragma unroll
    for (int r = 0; r < 4; r++) {
      int row = r * 32 + srow;
      int sc = sch ^ (row & 7);
      GLOAD16(Bk + (long)row * ldB + sc * 8, &lds[buf][1][(r * 32 + wave * 8) * BK]);
    }
  };

  stage(0, 0);
  stage(1, 1);
  asm volatile("s_waitcnt vmcnt(8)" ::: "memory");
  __builtin_amdgcn_sched_barrier(0);
  __builtin_amdgcn_s_barrier();

  int cur = 0;
  for (int kt = 0; kt < nk; kt++) {
    const short* La = lds[cur][0];
    const short* Lb = lds[cur][1];
    bf16x8 av[2][4], bv[2][4];
#pragma unroll
    for (int s = 0; s < 2; s++) {
#pragma unroll
      for (int i = 0; i < 4; i++) {
        av[s][i] = *reinterpret_cast<const bf16x8*>(La + aOff[i][s]);
        bv[s][i] = *reinterpret_cast<const bf16x8*>(Lb + bOff[i][s]);
      }
    }
    asm volatile("s_waitcnt lgkmcnt(0)" ::: "memory");
    __builtin_amdgcn_sched_barrier(0);
    __builtin_amdgcn_s_barrier();
    __builtin_amdgcn_sched_barrier(0);

    if (kt + 2 < nk) {
      stage(cur, kt + 2);
      asm volatile("s_waitcnt vmcnt(8)" ::: "memory");
    } else if (kt + 1 < nk) {
      asm volatile("s_waitcnt vmcnt(0)" ::: "memory");
    }
    if (kt + 1 < nk) {
      __builtin_amdgcn_s_barrier();
      __builtin_amdgcn_sched_barrier(0);
    }

    __builtin_amdgcn_s_setprio(1);
#pragma unroll
    for (int s = 0; s < 2; s++)
#pragma unroll
      for (int i = 0; i < 4; i++)
#pragma unroll
        for (int j = 0; j < 4; j++)
          acc[i][j] = __builtin_amdgcn_mfma_f32_16x16x32_bf16(av[s][i], bv[s][j], acc[i][j], 0, 0, 0);
    __builtin_amdgcn_s_setprio(0);
    __builtin_amdgcn_sched_barrier(0);
    cur ^= 1;
  }

  const int rb4 = (lane >> 4) * 4;
  const int cl = lane & 15;
#pragma unroll
  for (int i = 0; i < 4; i++) {
#pragma unroll
    for (int j = 0; j < 4; j++) {
      const int gm = m0 + wr * 64 + i * 16 + rb4;
      const int gn = n0 + wc * 64 + j * 16 + cl;
      float* C = Cv + (long)bz * cBat;
      const float bb = bias[gn];
#pragma unroll
      for (int r = 0; r < 4; r++)
        C[(long)(gm + r) * ldC + gn] = acc[i][j][r] + bb;
    }
  }
}

// one WAVE per (q row); 4 rows per block; shfl-only reduction.
__global__ __launch_bounds__(256)
void softmax_rows(const unsigned short* __restrict__ Sb, const float* __restrict__ maskv,
                  unsigned short* __restrict__ P, int Sdim)
{
  const int wv = threadIdx.x >> 6;
  const int lane = threadIdx.x & 63;
  const int q = blockIdx.x * 4 + wv;
  const int b = blockIdx.y;
  const int kmax = (q & ~127) + 128;
  const unsigned short* row = Sb + ((long)b * Sdim + q) * Sdim;
  unsigned short* prow = P + ((long)b * Sdim + q) * Sdim;
  const float* mrow = maskv + (long)b * Sdim;
  const float mq = mrow[q];

  float v[4][8];
  float mx = -INFINITY;
#pragma unroll
  for (int c = 0; c < 4; c++) {
    const int k0 = c * 512 + lane * 8;
    if (c * 512 < kmax) {
      uint4 raw = *reinterpret_cast<const uint4*>(row + k0);
      const unsigned short* us = reinterpret_cast<const unsigned short*>(&raw);
      float4 ma = *reinterpret_cast<const float4*>(mrow + k0);
      float4 mb = *reinterpret_cast<const float4*>(mrow + k0 + 4);
      float mv[8] = {ma.x, ma.y, ma.z, ma.w, mb.x, mb.y, mb.z, mb.w};
#pragma unroll
      for (int u = 0; u < 8; u++) {
        const int k = k0 + u;
        const bool ok = (k <= q) && (mq * mv[u] == 1.0f);   // square_mask == 1 semantics
        v[c][u] = ok ? bf2f(us[u]) : -INFINITY;
        mx = fmaxf(mx, v[c][u]);
      }
    } else {
#pragma unroll
      for (int u = 0; u < 8; u++) v[c][u] = -INFINITY;
    }
  }
#pragma unroll
  for (int o = 32; o; o >>= 1) mx = fmaxf(mx, __shfl_xor(mx, o));

  float sm = 0.f;
#pragma unroll
  for (int c = 0; c < 4; c++)
#pragma unroll
    for (int u = 0; u < 8; u++) {
      v[c][u] = (v[c][u] > -INFINITY) ? __expf(v[c][u] - mx) : 0.f;
      sm += v[c][u];
    }
#pragma unroll
  for (int o = 32; o; o >>= 1) sm += __shfl_xor(sm, o);
  const float inv = 1.0f / sm;

#pragma unroll
  for (int c = 0; c < 4; c++) {
    if (c * 512 < kmax) {
      union { unsigned short us[8]; uint4 u4; } pk;
#pragma unroll
      for (int u = 0; u < 8; u++) pk.us[u] = f2bf(v[c][u] * inv);
      *reinterpret_cast<uint4*>(prow + c * 512 + lane * 8) = pk.u4;
    }
  }
}

extern "C" void kernel_launch(void* const* d_in, const int* in_sizes, int n_in,
                              void* d_out, int out_size, void* d_ws, size_t ws_size,
                              hipStream_t stream)
{
  const int B = 4, S = 2048, D = 1024;
  const float* x  = (const float*)d_in[0];
  const float* mk = (const float*)d_in[1];
  const float* Wq = (const float*)d_in[2];
  const float* Wk = (const float*)d_in[3];
  const float* Wv = (const float*)d_in[4];
  const float* Wo = (const float*)d_in[5];
  const float* bo = (const float*)d_in[6];
  float* out = (float*)d_out;

  char* ws = (char*)d_ws;
  const long MB = 1024L * 1024L;
  unsigned short* Xbf  = (unsigned short*)(ws + 0);        // 16MB (live through dispA2)
  unsigned short* Qb   = (unsigned short*)(ws + 16 * MB);  // 16MB [8192][1024]; -> P
  unsigned short* Kb   = (unsigned short*)(ws + 32 * MB);  // 16MB [8192][1024]; -> P
  unsigned short* VWt  = (unsigned short*)(ws + 48 * MB);  // 16MB VW^T per batch [D][S]
  unsigned short* Wqk  = (unsigned short*)(ws + 64 * MB);  // 4MB [2048][1024] Wq|Wk
  unsigned short* Wvo  = (unsigned short*)(ws + 68 * MB);  // 2MB [1024][1024]
  unsigned short* Wob  = (unsigned short*)(ws + 70 * MB);  // 2MB
  unsigned short* Sbuf = (unsigned short*)(ws + 72 * MB);  // 32MB bf16 logits
  unsigned short* Wvt  = Sbuf;                             // 2MB overlay (dead before dispS)
  unsigned short* P    = Qb;                               // 32MB over dead Q+K

  if (ws_size < (size_t)(104 * MB)) {
    fprintf(stderr, "kernel_launch: ws too small (%zu bytes, need 104MB)\n", ws_size);
    return;
  }

  // 1) Wo cast + Wv transpose-cast (768 blocks) — only what Wvo consumes
  cast_ow<<<dim3(768), dim3(256), 0, stream>>>(Wo, Wv, Wob, Wvt);
  // 2) Wvo GEMM (bf16 GLOAD16, 64 blocks) hidden under x/Wq/Wk casts
  prep2<<<dim3(5184), dim3(256), 0, stream>>>(x, Wq, Wk, Wob, Wvt, Xbf, Wqk, Wvo);
  // 3) QK projection (1024) || VW = X*Wvo^T (512) — 2 clean rounds @3/CU
  dispA2<<<dim3(1536), dim3(256), 0, stream>>>(Xbf, Wqk, Wvo, Qb, Kb, VWt);
  // 4) S = Q K^T / 32, packed triangular (544 blocks, one round)
  dispS<<<dim3(544), dim3(256), 0, stream>>>(Qb, Kb, Sbuf);
  // 5) softmax -> P bf16
  softmax_rows<<<dim3(512, 4), dim3(256), 0, stream>>>(Sbuf, mk, P, 2048);
  // 6) out = P * VWt^T + bo (fp32 direct, causal K-limit, balanced pairing)
  dim3 gO(1024 / BN, 2048 / BM, 4);
  gemm_pv<<<gO, dim3(256), 0, stream>>>(P, VWt, out, bo,
                                        2048, 2048, 2048, 1024,
                                        (long)S * S, (long)D * S, (long)S * D);
}

// Round 15
// 151.655 us; speedup vs baseline: 1.2639x; 1.0279x over previous
//
#include <hip/hip_runtime.h>
#include <hip/hip_bf16.h>
#include <cstdio>

typedef __bf16 bf16x8 __attribute__((ext_vector_type(8)));
typedef float f32x4 __attribute__((ext_vector_type(4)));

#define BM 128
#define BN 128
#define BK 64

__device__ __forceinline__ unsigned short f2bf(float f) {
  union { float f; unsigned u; } v; v.f = f;
  unsigned u = v.u;
  return (unsigned short)((u + 0x7FFFu + ((u >> 16) & 1u)) >> 16);
}

#define GLOAD16(gsrc, ldst) \
  __builtin_amdgcn_global_load_lds((const __attribute__((address_space(1))) void*)(gsrc), \
                                   (__attribute__((address_space(3))) void*)(ldst), 16, 0, 0)

// ---------------------------------------------------------------------------
// Shared single-buffered K-loop body (m97-style, verified): ld == 1024, nk=16.
// LDS layout invariant: element (row, k) lives at shorts offset
//   row*64 + ((k>>3) ^ (row&7))*8 + (k&7)      (XOR-swizzled chunks)
// ---------------------------------------------------------------------------
#define SB_KLOOP(Ab, Bb)                                                        \
  for (int kt = 0; kt < 16; kt++) {                                             \
    const unsigned short* Ak = (Ab) + kt * BK;                                  \
    const unsigned short* Bk = (Bb) + kt * BK;                                  \
    _Pragma("unroll")                                                           \
    for (int r = 0; r < 4; r++) {                                               \
      int row = r * 32 + srow;                                                  \
      int sc = sch ^ (row & 7);                                                 \
      GLOAD16(Ak + (long)row * 1024 + sc * 8, &lds[0][(r * 32 + wave * 8) * BK]);\
    }                                                                           \
    _Pragma("unroll")                                                           \
    for (int r = 0; r < 4; r++) {                                               \
      int row = r * 32 + srow;                                                  \
      int sc = sch ^ (row & 7);                                                 \
      GLOAD16(Bk + (long)row * 1024 + sc * 8, &lds[1][(r * 32 + wave * 8) * BK]);\
    }                                                                           \
    __syncthreads();                                                            \
    _Pragma("unroll")                                                           \
    for (int s = 0; s < 2; s++) {                                               \
      bf16x8 av[4], bv[4];                                                      \
      _Pragma("unroll")                                                         \
      for (int i = 0; i < 4; i++) av[i] = *reinterpret_cast<const bf16x8*>(lds[0] + aOff[i][s]); \
      _Pragma("unroll")                                                         \
      for (int j = 0; j < 4; j++) bv[j] = *reinterpret_cast<const bf16x8*>(lds[1] + bOff[j][s]); \
      _Pragma("unroll")                                                         \
      for (int i = 0; i < 4; i++)                                               \
        _Pragma("unroll")                                                       \
        for (int j = 0; j < 4; j++)                                             \
          acc[i][j] = __builtin_amdgcn_mfma_f32_16x16x32_bf16(av[i], bv[j], acc[i][j], 0, 0, 0); \
    }                                                                           \
    __syncthreads();                                                            \
  }

#define SB_PREAMBLE                                                             \
  const int tid = threadIdx.x;                                                  \
  const int lane = tid & 63;                                                    \
  const int wave = tid >> 6;                                                    \
  const int wr = wave >> 1, wc = wave & 1;                                      \
  const int srow = tid >> 3;                                                    \
  const int sch = tid & 7;                                                      \
  (void)srow; (void)sch;                                                        \
  const f32x4 fzero = {0.f, 0.f, 0.f, 0.f};                                     \
  f32x4 acc[4][4];                                                              \
  _Pragma("unroll")                                                             \
  for (int i = 0; i < 4; i++)                                                   \
    _Pragma("unroll")                                                           \
    for (int j = 0; j < 4; j++) acc[i][j] = fzero;                              \
  int aOff[4][2], bOff[4][2];                                                   \
  _Pragma("unroll")                                                             \
  for (int i = 0; i < 4; i++) {                                                 \
    _Pragma("unroll")                                                           \
    for (int s = 0; s < 2; s++) {                                               \
      int ra = wr * 64 + i * 16 + (lane & 15);                                  \
      aOff[i][s] = ra * BK + (((s * 4 + (lane >> 4)) ^ (ra & 7)) * 8);          \
      int rb = wc * 64 + i * 16 + (lane & 15);                                  \
      bOff[i][s] = rb * BK + (((s * 4 + (lane >> 4)) ^ (rb & 7)) * 8);          \
    }                                                                           \
  }

// ---------------------------------------------------------------------------
// cast_ow: blocks [0,512) Wo cast -> Wob (bf16);
//          blocks [512,768) Wv transpose-cast -> Wvt[m][a] = Wv[a][m].
// ---------------------------------------------------------------------------
__global__ __launch_bounds__(256)
void cast_ow(const float* __restrict__ Wo, const float* __restrict__ Wv,
             unsigned short* __restrict__ Wob, unsigned short* __restrict__ Wvt)
{
  __shared__ float t[64][65];
  const int blk = blockIdx.x;
  const int tid = threadIdx.x;
  if (blk < 512) {
    const int i = (blk * 256 + tid) * 8;
    float4 a = *reinterpret_cast<const float4*>(Wo + i);
    float4 b = *reinterpret_cast<const float4*>(Wo + i + 4);
    union { unsigned short us[8]; uint4 u4; } pk;
    pk.us[0] = f2bf(a.x); pk.us[1] = f2bf(a.y); pk.us[2] = f2bf(a.z); pk.us[3] = f2bf(a.w);
    pk.us[4] = f2bf(b.x); pk.us[5] = f2bf(b.y); pk.us[6] = f2bf(b.z); pk.us[7] = f2bf(b.w);
    *reinterpret_cast<uint4*>(Wob + i) = pk.u4;
    return;
  }
  const int tile = blk - 512;                  // 0..255
  const int a0 = (tile >> 4) * 64;
  const int m0 = (tile & 15) * 64;
#pragma unroll
  for (int i = 0; i < 4; i++) {
    const int row = (tid >> 4) + i * 16;
    const int col4 = tid & 15;
    float4 f4 = *reinterpret_cast<const float4*>(Wv + (long)(a0 + row) * 1024 + m0 + col4 * 4);
    t[row][col4 * 4 + 0] = f4.x;
    t[row][col4 * 4 + 1] = f4.y;
    t[row][col4 * 4 + 2] = f4.z;
    t[row][col4 * 4 + 3] = f4.w;
  }
  __syncthreads();
#pragma unroll
  for (int j = 0; j < 2; j++) {
    const int mm = (tid >> 3) + j * 32;
    const int aa0 = (tid & 7) * 8;
    union { unsigned short us[8]; uint4 u4; } pk;
#pragma unroll
    for (int u = 0; u < 8; u++) pk.us[u] = f2bf(t[aa0 + u][mm]);
    *reinterpret_cast<uint4*>(Wvt + (long)(m0 + mm) * 1024 + a0 + aa0) = pk.u4;
  }
}

// ---------------------------------------------------------------------------
// prep2: blocks [0,64)       = Wvo = Wo*Wv GEMM (bf16 GLOAD16 — proven path);
//        blocks [64,4160)    = x-cast -> Xbf;
//        blocks [4160,5184)  = Wq/Wk casts -> Wqk.
// ---------------------------------------------------------------------------
__global__ __launch_bounds__(256, 3)
void prep2(const float* __restrict__ x, const float* __restrict__ Wq,
           const float* __restrict__ Wk,
           const unsigned short* __restrict__ Wob, const unsigned short* __restrict__ Wvt,
           unsigned short* __restrict__ xb, unsigned short* __restrict__ Wqk,
           unsigned short* __restrict__ Wvo)
{
  __shared__ short lds[2][BM * BK];
  const int blk = blockIdx.x;

  if (blk >= 64) {
    const int tid = threadIdx.x;
    const float* src;
    unsigned short* dst;
    int i;
    if (blk < 4160) {
      src = x; dst = xb; i = ((blk - 64) * 256 + tid) * 8;
    } else {
      const int w = (blk - 4160) >> 9;          // 0,1
      const int off = (blk - 4160) & 511;
      src = (w == 0) ? Wq : Wk;
      dst = Wqk + (long)w * 1024 * 1024;
      i = (off * 256 + tid) * 8;
    }
    float4 a = *reinterpret_cast<const float4*>(src + i);
    float4 b = *reinterpret_cast<const float4*>(src + i + 4);
    union { unsigned short us[8]; uint4 u4; } pk;
    pk.us[0] = f2bf(a.x); pk.us[1] = f2bf(a.y); pk.us[2] = f2bf(a.z); pk.us[3] = f2bf(a.w);
    pk.us[4] = f2bf(b.x); pk.us[5] = f2bf(b.y); pk.us[6] = f2bf(b.z); pk.us[7] = f2bf(b.w);
    *reinterpret_cast<uint4*>(dst + i) = pk.u4;
    return;
  }

  const int t = blk;                           // 0..63, 8x8 grid
  const int m0 = (t >> 3) * BM, n0 = (t & 7) * BN;
  const unsigned short* Ab = Wob + (long)m0 * 1024;
  const unsigned short* Bb = Wvt + (long)n0 * 1024;

  SB_PREAMBLE
  SB_KLOOP(Ab, Bb)

  const int rb4 = (lane >> 4) * 4;
  const int cl = lane & 15;
#pragma unroll
  for (int i = 0; i < 4; i++) {
#pragma unroll
    for (int j = 0; j < 4; j++) {
      const int gm = m0 + wr * 64 + i * 16 + rb4;
      const int gn = n0 + wc * 64 + j * 16 + cl;
#pragma unroll
      for (int r = 0; r < 4; r++)
        Wvo[(long)(gm + r) * 1024 + gn] = f2bf(acc[i][j][r]);
    }
  }
}

// ---------------------------------------------------------------------------
// dispA2: blocks [0,1024) = QK projection (M=8192, N=2048);
//         blocks [1024,1536) = VW = X*Wvo^T (transposed store -> VWt).
// ---------------------------------------------------------------------------
__global__ __launch_bounds__(256, 3)
void dispA2(const unsigned short* __restrict__ Xbf, const unsigned short* __restrict__ Wqk,
            const unsigned short* __restrict__ Wvo,
            unsigned short* __restrict__ Qb, unsigned short* __restrict__ Kb,
            unsigned short* __restrict__ VWt)
{
  __shared__ short lds[2][BM * BK];
  const int flat = blockIdx.x;
  const bool isQK = flat < 1024;
  int m0, n0;
  const unsigned short *Ab, *Bb;
  if (isQK) {
    const int swz = (flat & 7) * 128 + (flat >> 3);   // m204, nwg=1024 (r=0)
    const int bx = swz & 15, by = swz >> 4;           // gx=16
    m0 = by * BM; n0 = bx * BN;
    Ab = Xbf + (long)m0 * 1024;
    Bb = Wqk + (long)n0 * 1024;
  } else {
    const int t = flat - 1024;                        // 0..511
    const int swz = (t & 7) * 64 + (t >> 3);          // m204, nwg=512 (r=0)
    const int bx = swz & 7, by = swz >> 3;            // gx=8
    m0 = by * BM; n0 = bx * BN;
    Ab = Xbf + (long)m0 * 1024;
    Bb = Wvo + (long)n0 * 1024;
  }

  SB_PREAMBLE
  SB_KLOOP(Ab, Bb)

  const int rb4 = (lane >> 4) * 4;
  const int cl = lane & 15;
#pragma unroll
  for (int i = 0; i < 4; i++) {
#pragma unroll
    for (int j = 0; j < 4; j++) {
      const int gm = m0 + wr * 64 + i * 16 + rb4;
      const int gn = n0 + wc * 64 + j * 16 + cl;
      if (isQK) {
        if (gn < 1024) {
#pragma unroll
          for (int r = 0; r < 4; r++)
            Qb[(long)(gm + r) * 1024 + gn] = f2bf(acc[i][j][r]);
        } else {
#pragma unroll
          for (int r = 0; r < 4; r++)
            Kb[(long)(gm + r) * 1024 + (gn - 1024)] = f2bf(acc[i][j][r]);
        }
      } else {
        // transposed store: VWt[b][d=gn][s], b = gm>>11, s = gm&2047
        const int b = gm >> 11;
        const int sIdx = gm & 2047;
        unsigned short* C = VWt + (long)b * (2048L * 1024) + (long)gn * 2048 + sIdx;
        ushort4 pk;
        pk.x = f2bf(acc[i][j][0]);
        pk.y = f2bf(acc[i][j][1]);
        pk.z = f2bf(acc[i][j][2]);
        pk.w = f2bf(acc[i][j][3]);
        *reinterpret_cast<ushort4*>(C) = pk;
      }
    }
  }
}

// ---------------------------------------------------------------------------
// dispS: E = exp((Q K^T)/32) with causal+padding mask fused in the epilogue.
// Packed lower-triangular (136 tiles x 4 batches). Writes bf16 E (0 masked).
// Logits ~ N(0,1) after /32 -> exp is safe without max subtraction.
// ---------------------------------------------------------------------------
__global__ __launch_bounds__(256, 3)
void dispS(const unsigned short* __restrict__ Qb, const unsigned short* __restrict__ Kb,
           const float* __restrict__ mk, unsigned short* __restrict__ Eb)
{
  __shared__ short lds[2][BM * BK];
  const int t = blockIdx.x;                           // 0..543
  const int bz = t / 136;
  const int tt = t - bz * 136;
  const int swz = (tt & 7) * 17 + (tt >> 3);          // m204, nwg=136 (17x8, r=0)
  int i = (int)((sqrtf(8.f * (float)swz + 1.f) - 1.f) * 0.5f);
  while ((i + 1) * (i + 2) / 2 <= swz) ++i;
  while (i * (i + 1) / 2 > swz) --i;
  const int j = swz - i * (i + 1) / 2;
  const int m0 = i * BM, n0 = j * BN;
  const unsigned short* Ab = Qb + ((long)bz * 2048 + m0) * 1024;
  const unsigned short* Bb = Kb + ((long)bz * 2048 + n0) * 1024;

  SB_PREAMBLE
  SB_KLOOP(Ab, Bb)

  const int rb4 = (lane >> 4) * 4;
  const int cl = lane & 15;
  unsigned short* C = Eb + (long)bz * (2048L * 2048);
  const float* mrow = mk + (long)bz * 2048;
#pragma unroll
  for (int ii = 0; ii < 4; ii++) {
#pragma unroll
    for (int jj = 0; jj < 4; jj++) {
      const int gm = m0 + wr * 64 + ii * 16 + rb4;
      const int gn = n0 + wc * 64 + jj * 16 + cl;
      const float mv = mrow[gn];
#pragma unroll
      for (int r = 0; r < 4; r++) {
        const int row = gm + r;
        const bool ok = (gn <= row) && (mrow[row] * mv == 1.0f);  // square_mask == 1
        const float e = ok ? __expf(acc[ii][jj][r] * 0.03125f) : 0.f;
        C[(long)row * 2048 + gn] = f2bf(e);
      }
    }
  }
}

// ---------------------------------------------------------------------------
// gemm_pv: out = (E · VWt^T) * rowinv + bias.  Double-buffered counted-vmcnt;
// rowsum recovered in-GEMM via ones-vector MFMA (B=1 -> every C column = row
// sum of A, in the same C/D fragment layout as acc). Balanced causal pairing.
// ---------------------------------------------------------------------------
__global__ __launch_bounds__(256, 2)
void gemm_pv(const unsigned short* __restrict__ A, const unsigned short* __restrict__ B,
             float* __restrict__ Cv, const float* __restrict__ bias,
             int K, int ldA, int ldB, int ldC,
             long aBat, long bBat, long cBat)
{
  const int gx = gridDim.x;
  const int nwg = gx * gridDim.y;
  const int flat = blockIdx.y * gx + blockIdx.x;
  const int qch = nwg >> 3, rch = nwg & 7;
  const int xcd = flat & 7, idx = flat >> 3;
  const int swz = (xcd < rch ? xcd * (qch + 1) : rch * (qch + 1) + (xcd - rch) * qch) + idx;
  const int bx = swz % gx;
  const int bz = blockIdx.z;
  int by = swz / gx;
  if (bz >= 2) by = gridDim.y - 1 - by;      // complementary-Keff pairing

  const int m0 = by * BM;
  const int n0 = bx * BN;

  const unsigned short* Ab = A + (long)bz * aBat + (long)m0 * ldA;
  const unsigned short* Bb = B + (long)bz * bBat + (long)n0 * ldB;

  __shared__ short lds[2][2][BM * BK];

  const int tid = threadIdx.x;
  const int lane = tid & 63;
  const int wave = tid >> 6;
  const int wr = wave >> 1, wc = wave & 1;

  const int Keff = min(K, m0 + BM);          // causal K-limit
  const int nk = Keff / BK;

  const int srow = tid >> 3;
  const int sch = tid & 7;

  const f32x4 fzero = {0.f, 0.f, 0.f, 0.f};
  f32x4 acc[4][4];
  f32x4 accs[4];                             // rowsum accumulators
#pragma unroll
  for (int i = 0; i < 4; i++) {
    accs[i] = fzero;
#pragma unroll
    for (int j = 0; j < 4; j++) acc[i][j] = fzero;
  }
  bf16x8 vone;
#pragma unroll
  for (int u = 0; u < 8; u++) vone[u] = (__bf16)1.0f;

  int aOff[4][2], bOff[4][2];
#pragma unroll
  for (int i = 0; i < 4; i++) {
#pragma unroll
    for (int s = 0; s < 2; s++) {
      int ra = wr * 64 + i * 16 + (lane & 15);
      aOff[i][s] = ra * BK + (((s * 4 + (lane >> 4)) ^ (ra & 7)) * 8);
      int rb = wc * 64 + i * 16 + (lane & 15);
      bOff[i][s] = rb * BK + (((s * 4 + (lane >> 4)) ^ (rb & 7)) * 8);
    }
  }

  auto stage = [&](int buf, int kt) {
    const unsigned short* Ak = Ab + kt * BK;
    const unsigned short* Bk = Bb + kt * BK;
#pragma unroll
    for (int r = 0; r < 4; r++) {
      int row = r * 32 + srow;
      int sc = sch ^ (row & 7);
      GLOAD16(Ak + (long)row * ldA + sc * 8, &lds[buf][0][(r * 32 + wave * 8) * BK]);
    }
#pragma unroll
    for (int r = 0; r < 4; r++) {
      int row = r * 32 + srow;
      int sc = sch ^ (row & 7);
      GLOAD16(Bk + (long)row * ldB + sc * 8, &lds[buf][1][(r * 32 + wave * 8) * BK]);
    }
  };

  stage(0, 0);
  stage(1, 1);
  asm volatile("s_waitcnt vmcnt(8)" ::: "memory");
  __builtin_amdgcn_sched_barrier(0);
  __builtin_amdgcn_s_barrier();

  int cur = 0;
  for (int kt = 0; kt < nk; kt++) {
    const short* La = lds[cur][0];
    const short* Lb = lds[cur][1];
    bf16x8 av[2][4], bv[2][4];
#pragma unroll
    for (int s = 0; s < 2; s++) {
#pragma unroll
      for (int i = 0; i < 4; i++) {
        av[s][i] = *reinterpret_cast<const bf16x8*>(La + aOff[i][s]);
        bv[s][i] = *reinterpret_cast<const bf16x8*>(Lb + bOff[i][s]);
      }
    }
    asm volatile("s_waitcnt lgkmcnt(0)" ::: "memory");
    __builtin_amdgcn_sched_barrier(0);
    __builtin_amdgcn_s_barrier();
    __builtin_amdgcn_sched_barrier(0);

    if (kt + 2 < nk) {
      stage(cur, kt + 2);
      asm volatile("s_waitcnt vmcnt(8)" ::: "memory");
    } else if (kt + 1 < nk) {
      asm volatile("s_waitcnt vmcnt(0)" ::: "memory");
    }
    if (kt + 1 < nk) {
      __builtin_amdgcn_s_barrier();
      __builtin_amdgcn_sched_barrier(0);
    }

    __builtin_amdgcn_s_setprio(1);
#pragma unroll
    for (int s = 0; s < 2; s++) {
#pragma unroll
      for (int i = 0; i < 4; i++)
#pragma unroll
        for (int j = 0; j < 4; j++)
          acc[i][j] = __builtin_amdgcn_mfma_f32_16x16x32_bf16(av[s][i], bv[s][j], acc[i][j], 0, 0, 0);
#pragma unroll
      for (int i = 0; i < 4; i++)
        accs[i] = __builtin_amdgcn_mfma_f32_16x16x32_bf16(av[s][i], vone, accs[i], 0, 0, 0);
    }
    __builtin_amdgcn_s_setprio(0);
    __builtin_amdgcn_sched_barrier(0);
    cur ^= 1;
  }

  const int rb4 = (lane >> 4) * 4;
  const int cl = lane & 15;
#pragma unroll
  for (int i = 0; i < 4; i++) {
    float invr[4];
#pragma unroll
    for (int r = 0; r < 4; r++) invr[r] = 1.0f / accs[i][r];
#pragma unroll
    for (int j = 0; j < 4; j++) {
      const int gm = m0 + wr * 64 + i * 16 + rb4;
      const int gn = n0 + wc * 64 + j * 16 + cl;
      float* C = Cv + (long)bz * cBat;
      const float bb = bias[gn];
#pragma unroll
      for (int r = 0; r < 4; r++)
        C[(long)(gm + r) * ldC + gn] = acc[i][j][r] * invr[r] + bb;
    }
  }
}

extern "C" void kernel_launch(void* const* d_in, const int* in_sizes, int n_in,
                              void* d_out, int out_size, void* d_ws, size_t ws_size,
                              hipStream_t stream)
{
  const int B = 4, S = 2048, D = 1024;
  const float* x  = (const float*)d_in[0];
  const float* mk = (const float*)d_in[1];
  const float* Wq = (const float*)d_in[2];
  const float* Wk = (const float*)d_in[3];
  const float* Wv = (const float*)d_in[4];
  const float* Wo = (const float*)d_in[5];
  const float* bo = (const float*)d_in[6];
  float* out = (float*)d_out;

  char* ws = (char*)d_ws;
  const long MB = 1024L * 1024L;
  unsigned short* Xbf  = (unsigned short*)(ws + 0);        // 16MB (live through dispA2)
  unsigned short* Qb   = (unsigned short*)(ws + 16 * MB);  // 16MB [8192][1024]
  unsigned short* Kb   = (unsigned short*)(ws + 32 * MB);  // 16MB [8192][1024]
  unsigned short* VWt  = (unsigned short*)(ws + 48 * MB);  // 16MB VW^T per batch [D][S]
  unsigned short* Wqk  = (unsigned short*)(ws + 64 * MB);  // 4MB [2048][1024] Wq|Wk
  unsigned short* Wvo  = (unsigned short*)(ws + 68 * MB);  // 2MB [1024][1024]
  unsigned short* Wob  = (unsigned short*)(ws + 70 * MB);  // 2MB
  unsigned short* Ebuf = (unsigned short*)(ws + 72 * MB);  // 32MB bf16 exp-logits
  unsigned short* Wvt  = Ebuf;                             // 2MB overlay (dead before dispS)

  if (ws_size < (size_t)(104 * MB)) {
    fprintf(stderr, "kernel_launch: ws too small (%zu bytes, need 104MB)\n", ws_size);
    return;
  }

  // 1) Wo cast + Wv transpose-cast (768 blocks)
  cast_ow<<<dim3(768), dim3(256), 0, stream>>>(Wo, Wv, Wob, Wvt);
  // 2) Wvo GEMM (bf16 GLOAD16, 64 blocks) hidden under x/Wq/Wk casts
  prep2<<<dim3(5184), dim3(256), 0, stream>>>(x, Wq, Wk, Wob, Wvt, Xbf, Wqk, Wvo);
  // 3) QK projection (1024) || VW = X*Wvo^T (512) — 2 clean rounds @3/CU
  dispA2<<<dim3(1536), dim3(256), 0, stream>>>(Xbf, Wqk, Wvo, Qb, Kb, VWt);
  // 4) E = exp(Q K^T / 32) masked, packed triangular (544 blocks)
  dispS<<<dim3(544), dim3(256), 0, stream>>>(Qb, Kb, mk, Ebuf);
  // 5) out = (E · VWt^T) * rowinv + bo — softmax normalizer fused via ones-MFMA
  dim3 gO(1024 / BN, 2048 / BM, 4);
  gemm_pv<<<gO, dim3(256), 0, stream>>>(Ebuf, VWt, out, bo,
                                        2048, 2048, 2048, 1024,
                                        (long)S * S, (long)D * S, (long)S * D);
}